// Round 6
// baseline (95.827 us; speedup 1.0000x reference)
//
#include <hip/hip_runtime.h>

#define BD 128   // D
#define SL 512   // L
#define NB 4     // B

__device__ __forceinline__ float rcp_fast(float x) { return __builtin_amdgcn_rcpf(x); }

// K0: transpose Wu, Ww (row-major (out,in)) -> WT[k][o]. 64 blocks, trivial.
__global__ __launch_bounds__(256) void k_tr(const float* __restrict__ Wu,
                                            const float* __restrict__ Ww,
                                            float* __restrict__ WuT,
                                            float* __restrict__ WwT) {
    int idx = blockIdx.x * 256 + threadIdx.x;   // 0..16383
    int k = idx >> 7, o = idx & 127;
    WuT[idx] = Wu[o * BD + k];
    WwT[idx] = Ww[o * BD + k];
}

// K1: qu = inp@Wu.T, kw = inp@Ww.T. 4 rows/block, 512 blocks.
// t<128 -> qu col o, t>=128 -> kw col o. Equ packed [b][d>>2][l][d&3]; Ekw (b,l,d).
__global__ __launch_bounds__(256) void k_qk(const float* __restrict__ inp,
                                            const float* __restrict__ WuT,
                                            const float* __restrict__ WwT,
                                            float* __restrict__ Equ,
                                            float* __restrict__ Ekw) {
    __shared__ float sx[4][BD];
    const int t = threadIdx.x, m = t >> 7, o = t & 127;
    const int r0 = blockIdx.x * 4;          // global row = b*SL + l
    const int b  = r0 >> 9;
    const int l0 = r0 & (SL - 1);

    #pragma unroll
    for (int h = 0; h < 2; ++h) {
        int id = h * 256 + t;               // 0..511
        sx[id >> 7][id & 127] = inp[(size_t)r0 * BD + id];   // coalesced
    }
    __syncthreads();

    const float* WT = m ? WwT : WuT;        // WT[k][o], coalesced + L2-hot
    float acc[4] = {0.f, 0.f, 0.f, 0.f};
    #pragma unroll 2
    for (int k = 0; k < BD; k += 4) {
        float w0 = WT[(k + 0) * BD + o];
        float w1 = WT[(k + 1) * BD + o];
        float w2 = WT[(k + 2) * BD + o];
        float w3 = WT[(k + 3) * BD + o];
        #pragma unroll
        for (int rr = 0; rr < 4; ++rr) {
            float4 x = *(const float4*)&sx[rr][k];   // b128 broadcast
            acc[rr] = fmaf(x.x, w0, acc[rr]);
            acc[rr] = fmaf(x.y, w1, acc[rr]);
            acc[rr] = fmaf(x.z, w2, acc[rr]);
            acc[rr] = fmaf(x.w, w3, acc[rr]);
        }
    }

    if (m == 0) {
        #pragma unroll
        for (int rr = 0; rr < 4; ++rr)
            Equ[(((size_t)b * 32 + (o >> 2)) * SL + (l0 + rr)) * 4 + (o & 3)] =
                __expf(2.f * acc[rr]);
    } else {
        #pragma unroll
        for (int rr = 0; rr < 4; ++rr)
            Ekw[(size_t)(r0 + rr) * BD + o] = __expf(2.f * acc[rr]);
    }
}

// K2: block = (b, 4 query rows), 1024 threads, lean VGPR -> 2 blocks/CU (8 waves/SIMD).
// Phase 1 d-split: t<512 -> d 0..63, else d 64..127; j = t&511; 4 rcp chains.
// Phase 2: each d-half owns 2 rows. Phase 3: 16 j-chunk waves, b128 staging, 16-way reduce.
__global__ __launch_bounds__(1024, 8) void k_attn(const float* __restrict__ inp,
                                                  const float* __restrict__ Wv,
                                                  const float* __restrict__ Equ,
                                                  const float* __restrict__ Ekw,
                                                  float* __restrict__ out,
                                                  float* __restrict__ attn) {
    __shared__ float4 smem4[(SL * 4 + 16 * 4 * BD) / 4];   // 40 KB
    float* smem  = (float*)smem4;
    float* s_pT  = smem;                  // [SL][4] attn transposed (rows 0..3)
    float* ovl   = smem + SL * 4;         // overlay: phase1/2 scratch, then s_fin
    float4* s_e  = (float4*)ovl;          // [BD] Ekw rows 0..3 per d
    float*  s_wv = ovl + 512;             // [BD]
    float*  s_ap = ovl + 640;             // [4][SL] partial a exchange
    float*  s_red= ovl + 640 + 4 * SL;    // [4][8]
    float*  s_fin= ovl;                   // [16][4][BD] phase-3 partials (32 KB)

    const int t  = threadIdx.x;
    const int b  = blockIdx.x >> 7;
    const int i0 = (blockIdx.x & 127) * 4;

    if (t < BD) {
        const float* ek = Ekw + ((size_t)b * SL + i0) * BD + t;
        s_e[t]  = make_float4(ek[0], ek[BD], ek[2 * BD], ek[3 * BD]);
        s_wv[t] = Wv[t];
    }
    __syncthreads();

    // ---- Phase 1: a[i] = sum_{d in half} wv/(1+Equ[d][j]*Ekw[i][d]) ----
    const int j = t & 511, dh = t >> 9;
    const float4* equ4 = (const float4*)(Equ + (size_t)b * BD * SL);
    float a[4] = {0.f, 0.f, 0.f, 0.f};
    #pragma unroll 4
    for (int cc = 0; cc < 16; ++cc) {
        int c = dh * 16 + cc;
        float4 q = equ4[c * SL + j];        // coalesced 1KB/wave, 4 d-values
        float qs[4] = {q.x, q.y, q.z, q.w};
        #pragma unroll
        for (int dd = 0; dd < 4; ++dd) {
            int d = c * 4 + dd;
            float4 e = s_e[d];              // wave-uniform b128 broadcast
            float  w = s_wv[d];
            float  qd = qs[dd];
            a[0] = fmaf(w, rcp_fast(fmaf(qd, e.x, 1.f)), a[0]);
            a[1] = fmaf(w, rcp_fast(fmaf(qd, e.y, 1.f)), a[1]);
            a[2] = fmaf(w, rcp_fast(fmaf(qd, e.z, 1.f)), a[2]);
            a[3] = fmaf(w, rcp_fast(fmaf(qd, e.w, 1.f)), a[3]);
        }
    }

    // Combine d-halves: dh posts the other half's 2 rows, keeps rows ro..ro+1.
    const int ro = dh * 2, wo = 2 - ro;
    s_ap[(wo + 0) * SL + j] = a[wo + 0];
    s_ap[(wo + 1) * SL + j] = a[wo + 1];
    __syncthreads();
    float af[2] = { a[ro + 0] + s_ap[(ro + 0) * SL + j],
                    a[ro + 1] + s_ap[(ro + 1) * SL + j] };

    // ---- Phase 2: softmax over j of score = -2*af (reduce MIN of af) ----
    const int w8 = j >> 6;
    float mn[2] = { af[0], af[1] };
    #pragma unroll
    for (int off = 32; off > 0; off >>= 1) {
        mn[0] = fminf(mn[0], __shfl_xor(mn[0], off, 64));
        mn[1] = fminf(mn[1], __shfl_xor(mn[1], off, 64));
    }
    if ((j & 63) == 0) { s_red[(ro + 0) * 8 + w8] = mn[0]; s_red[(ro + 1) * 8 + w8] = mn[1]; }
    __syncthreads();
    #pragma unroll
    for (int ii = 0; ii < 2; ++ii) {
        float4 r0 = *(const float4*)&s_red[(ro + ii) * 8];
        float4 r1 = *(const float4*)&s_red[(ro + ii) * 8 + 4];
        mn[ii] = fminf(fminf(fminf(r0.x, r0.y), fminf(r0.z, r0.w)),
                       fminf(fminf(r1.x, r1.y), fminf(r1.z, r1.w)));
    }

    float p[2] = { __expf(-2.f * (af[0] - mn[0])), __expf(-2.f * (af[1] - mn[1])) };
    float sm[2] = { p[0], p[1] };
    #pragma unroll
    for (int off = 32; off > 0; off >>= 1) {
        sm[0] += __shfl_xor(sm[0], off, 64);
        sm[1] += __shfl_xor(sm[1], off, 64);
    }
    __syncthreads();                        // finish min-reads before s_red reuse
    if ((j & 63) == 0) { s_red[(ro + 0) * 8 + w8] = sm[0]; s_red[(ro + 1) * 8 + w8] = sm[1]; }
    __syncthreads();
    float n[2];
    #pragma unroll
    for (int ii = 0; ii < 2; ++ii) {
        float4 r0 = *(const float4*)&s_red[(ro + ii) * 8];
        float4 r1 = *(const float4*)&s_red[(ro + ii) * 8 + 4];
        float rs = rcp_fast((r0.x + r0.y) + (r0.z + r0.w) + (r1.x + r1.y) + (r1.z + r1.w));
        n[ii] = p[ii] * rs;
        attn[((size_t)b * SL + i0 + ro + ii) * SL + j] = n[ii];   // coalesced
    }
    ((float2*)s_pT)[j * 2 + dh] = make_float2(n[0], n[1]);
    __syncthreads();

    // ---- Phase 3: out = attn @ inp; wave g covers j = g*32..g*32+31 ----
    const int g  = t >> 6;                  // 16 waves
    const int ln = t & 63;
    const int dq = ln & 31;                 // d-quad (d = dq*4..dq*4+3)
    const int rh = ln >> 5;                 // row pair: rows rh*2, rh*2+1
    const float4* inp4 = (const float4*)(inp + (size_t)b * SL * BD);
    float4 acc0 = make_float4(0.f, 0.f, 0.f, 0.f);
    float4 acc1 = make_float4(0.f, 0.f, 0.f, 0.f);
    #pragma unroll 4
    for (int jj = 0; jj < 32; ++jj) {
        int jr = g * 32 + jj;
        float4 x  = inp4[jr * 32 + dq];                    // L2-hit b128
        float2 pp = ((const float2*)s_pT)[jr * 2 + rh];    // 2-addr LDS broadcast
        acc0.x = fmaf(pp.x, x.x, acc0.x); acc0.y = fmaf(pp.x, x.y, acc0.y);
        acc0.z = fmaf(pp.x, x.z, acc0.z); acc0.w = fmaf(pp.x, x.w, acc0.w);
        acc1.x = fmaf(pp.y, x.x, acc1.x); acc1.y = fmaf(pp.y, x.y, acc1.y);
        acc1.z = fmaf(pp.y, x.z, acc1.z); acc1.w = fmaf(pp.y, x.w, acc1.w);
    }
    // s_fin overlays s_ap/s_e (no longer read); s_pT untouched.
    *(float4*)&s_fin[((g * 4) + rh * 2 + 0) * BD + dq * 4] = acc0;
    *(float4*)&s_fin[((g * 4) + rh * 2 + 1) * BD + dq * 4] = acc1;
    __syncthreads();
    if (t < 512) {
        int row = t >> 7, d = t & 127;
        float s = 0.f;
        #pragma unroll
        for (int gg = 0; gg < 16; ++gg)
            s += s_fin[(gg * 4 + row) * BD + d];           // conflict-free
        out[((size_t)b * SL + i0 + row) * BD + d] = s;     // coalesced
    }
}

extern "C" void kernel_launch(void* const* d_in, const int* in_sizes, int n_in,
                              void* d_out, int out_size, void* d_ws, size_t ws_size,
                              hipStream_t stream) {
    const float* inp = (const float*)d_in[0];
    const float* Wu  = (const float*)d_in[1];
    const float* Ww  = (const float*)d_in[2];
    const float* Wv  = (const float*)d_in[3];

    float* out  = (float*)d_out;
    float* attn = out + (size_t)NB * SL * BD;     // out (B,L,D) then attn (B,L,L)

    float* ws  = (float*)d_ws;
    float* Equ = ws;                              // (B, D/4, L, 4) packed exp(2*qu)
    float* Ekw = Equ + (size_t)NB * BD * SL;      // (B, L, D) exp(2*kw)
    float* WuT = Ekw + (size_t)NB * SL * BD;
    float* WwT = WuT + BD * BD;

    k_tr  <<<BD * BD / 256, 256, 0, stream>>>(Wu, Ww, WuT, WwT);
    k_qk  <<<NB * SL / 4, 256, 0, stream>>>(inp, WuT, WwT, Equ, Ekw);
    k_attn<<<NB * SL / 4, 1024, 0, stream>>>(inp, Wv, Equ, Ekw, out, attn);
}

// Round 7
// 94.936 us; speedup vs baseline: 1.0094x; 1.0094x over previous
//
#include <hip/hip_runtime.h>

#define BD 128   // D
#define SL 512   // L
#define NB 4     // B

__device__ __forceinline__ float rcp_fast(float x) { return __builtin_amdgcn_rcpf(x); }

// K0: transpose Wu, Ww (row-major (out,in)) -> WT[k][o]. 64 blocks, trivial.
__global__ __launch_bounds__(256) void k_tr(const float* __restrict__ Wu,
                                            const float* __restrict__ Ww,
                                            float* __restrict__ WuT,
                                            float* __restrict__ WwT) {
    int idx = blockIdx.x * 256 + threadIdx.x;   // 0..16383
    int k = idx >> 7, o = idx & 127;
    WuT[idx] = Wu[o * BD + k];
    WwT[idx] = Ww[o * BD + k];
}

// K1: qu = inp@Wu.T, kw = inp@Ww.T. 2 rows/block, 1024 blocks (4/CU -> latency hidden).
// t<128 -> qu col o, t>=128 -> kw col o.
// Equ2 packed [b][d>>2][j>>1][ (j&1)*4 + (d&3) ] so k_attn reads a j-pair with 2 b128.
__global__ __launch_bounds__(256) void k_qk(const float* __restrict__ inp,
                                            const float* __restrict__ WuT,
                                            const float* __restrict__ WwT,
                                            float* __restrict__ Equ2,
                                            float* __restrict__ Ekw) {
    __shared__ float sx[2][BD];
    const int t = threadIdx.x, m = t >> 7, o = t & 127;
    const int r0 = blockIdx.x * 2;          // global row = b*SL + l  (l0 even)
    const int b  = r0 >> 9;
    const int l0 = r0 & (SL - 1);
    const int jp = l0 >> 1;

    sx[t >> 7][t & 127] = inp[(size_t)r0 * BD + t];   // coalesced 512 floats
    __syncthreads();

    const float* WT = m ? WwT : WuT;        // WT[k][o], coalesced + L2-hot
    float acc0 = 0.f, acc1 = 0.f;
    #pragma unroll 4
    for (int k = 0; k < BD; k += 4) {       // unroll 4 -> 16 loads in flight
        float w0 = WT[(k + 0) * BD + o];
        float w1 = WT[(k + 1) * BD + o];
        float w2 = WT[(k + 2) * BD + o];
        float w3 = WT[(k + 3) * BD + o];
        float4 x0 = *(const float4*)&sx[0][k];   // b128 broadcast
        float4 x1 = *(const float4*)&sx[1][k];
        acc0 = fmaf(x0.x, w0, acc0); acc0 = fmaf(x0.y, w1, acc0);
        acc0 = fmaf(x0.z, w2, acc0); acc0 = fmaf(x0.w, w3, acc0);
        acc1 = fmaf(x1.x, w0, acc1); acc1 = fmaf(x1.y, w1, acc1);
        acc1 = fmaf(x1.z, w2, acc1); acc1 = fmaf(x1.w, w3, acc1);
    }

    if (m == 0) {
        size_t base = (((size_t)b * 32 + (o >> 2)) * 256 + jp) * 8 + (o & 3);
        Equ2[base]     = __expf(2.f * acc0);   // jj=0
        Equ2[base + 4] = __expf(2.f * acc1);   // jj=1
    } else {
        Ekw[(size_t)(r0 + 0) * BD + o] = __expf(2.f * acc0);
        Ekw[(size_t)(r0 + 1) * BD + o] = __expf(2.f * acc1);
    }
}

// K2: block = (b, 4 query rows), 1024 threads, 2 blocks/CU.
// P1: thread (jp = t&255, dg = t>>8) handles j in {2jp,2jp+1}, d in [dg*32, dg*32+32),
//     all 4 i. contribution = wv/(1+q*e) = rcp(fma(q, E, u)) with u=1/wv, E=e*u
//     -> LDS broadcasts amortized over the j-pair (2x fewer LDS instrs than R5).
// P2: 4-way d-combine via s_ap, then softmax (thread = (j, row-pair)).
// P3: 16 j-chunk waves, b128 staging, 16-way LDS reduce.
__global__ __launch_bounds__(1024, 8) void k_attn(const float* __restrict__ inp,
                                                  const float* __restrict__ Wv,
                                                  const float* __restrict__ Equ2,
                                                  const float* __restrict__ Ekw,
                                                  float* __restrict__ out,
                                                  float* __restrict__ attn) {
    __shared__ float4 smem4[(SL * 4 + 8960) / 4];   // ~44 KB
    float* smem  = (float*)smem4;
    float* s_pT  = smem;                  // [SL][4] attn (row-minor)
    float* ovl   = smem + SL * 4;         // overlay region
    float4* s_E  = (float4*)ovl;          // [BD] {e_i * u} for i=0..3          (0..511)
    float*  s_u  = ovl + 512;             // [BD] 1/wv                          (512..639)
    float*  s_ap = ovl;                   // [dg][jj][i][jp] = [4][2][4][256]   (0..8191) after P1
    float*  s_rA = ovl + 8704;            // [4][8] min-reduce
    float*  s_rB = ovl + 8736;            // [4][8] sum-reduce
    float*  s_fin= ovl;                   // [16][4][BD] phase-3 partials (32 KB)

    const int t  = threadIdx.x;
    const int b  = blockIdx.x >> 7;
    const int i0 = (blockIdx.x & 127) * 4;

    // s_ap overlays s_E/s_u: stage into registers first, then barrier, then write LDS.
    float4 eE; float eu;
    if (t < BD) {
        const float* ek = Ekw + ((size_t)b * SL + i0) * BD + t;
        float e0 = ek[0], e1 = ek[BD], e2 = ek[2 * BD], e3 = ek[3 * BD];
        eu = rcp_fast(Wv[t]);
        eE = make_float4(e0 * eu, e1 * eu, e2 * eu, e3 * eu);
    }
    if (t < BD) { s_E[t] = eE; s_u[t] = eu; }
    __syncthreads();                                         // sync 1

    // ---- Phase 1 ----
    const int jp = t & 255, dg = t >> 8;
    const float4* equ4 = (const float4*)(Equ2 + (size_t)b * BD * SL);
    float a0[4] = {0.f, 0.f, 0.f, 0.f};   // j = 2jp
    float a1[4] = {0.f, 0.f, 0.f, 0.f};   // j = 2jp+1
    #pragma unroll 2
    for (int cc = 0; cc < 8; ++cc) {
        int c = dg * 8 + cc;
        float4 qA = equ4[(c * 256 + jp) * 2 + 0];   // j=2jp,   d=4c..4c+3
        float4 qB = equ4[(c * 256 + jp) * 2 + 1];   // j=2jp+1
        float qa[4] = {qA.x, qA.y, qA.z, qA.w};
        float qb[4] = {qB.x, qB.y, qB.z, qB.w};
        #pragma unroll
        for (int dd = 0; dd < 4; ++dd) {
            int d = c * 4 + dd;
            float4 E = s_E[d];             // wave-uniform b128 broadcast
            float  u = s_u[d];             // wave-uniform b32 broadcast
            a0[0] += rcp_fast(fmaf(qa[dd], E.x, u));
            a0[1] += rcp_fast(fmaf(qa[dd], E.y, u));
            a0[2] += rcp_fast(fmaf(qa[dd], E.z, u));
            a0[3] += rcp_fast(fmaf(qa[dd], E.w, u));
            a1[0] += rcp_fast(fmaf(qb[dd], E.x, u));
            a1[1] += rcp_fast(fmaf(qb[dd], E.y, u));
            a1[2] += rcp_fast(fmaf(qb[dd], E.z, u));
            a1[3] += rcp_fast(fmaf(qb[dd], E.w, u));
        }
    }
    __syncthreads();                                         // sync 2 (s_E/s_u done)
    #pragma unroll
    for (int i = 0; i < 4; ++i) {
        s_ap[((dg * 2 + 0) * 4 + i) * 256 + jp] = a0[i];     // conflict-free b32
        s_ap[((dg * 2 + 1) * 4 + i) * 256 + jp] = a1[i];
    }
    __syncthreads();                                         // sync 3

    // ---- Phase 2 ----
    const int j = t & 511, dh = t >> 9, ro = dh * 2;
    const int jpp = j >> 1, jj = j & 1, w8 = j >> 6;
    float af[2];
    #pragma unroll
    for (int ii = 0; ii < 2; ++ii) {
        int r = ro + ii;
        af[ii] = s_ap[((0 * 2 + jj) * 4 + r) * 256 + jpp]    // 2-lane broadcast reads
               + s_ap[((1 * 2 + jj) * 4 + r) * 256 + jpp]
               + s_ap[((2 * 2 + jj) * 4 + r) * 256 + jpp]
               + s_ap[((3 * 2 + jj) * 4 + r) * 256 + jpp];
    }

    float mn[2] = { af[0], af[1] };
    #pragma unroll
    for (int off = 32; off > 0; off >>= 1) {
        mn[0] = fminf(mn[0], __shfl_xor(mn[0], off, 64));
        mn[1] = fminf(mn[1], __shfl_xor(mn[1], off, 64));
    }
    if ((j & 63) == 0) { s_rA[(ro + 0) * 8 + w8] = mn[0]; s_rA[(ro + 1) * 8 + w8] = mn[1]; }
    __syncthreads();                                         // sync 4
    #pragma unroll
    for (int ii = 0; ii < 2; ++ii) {
        float4 r0 = *(const float4*)&s_rA[(ro + ii) * 8];
        float4 r1 = *(const float4*)&s_rA[(ro + ii) * 8 + 4];
        mn[ii] = fminf(fminf(fminf(r0.x, r0.y), fminf(r0.z, r0.w)),
                       fminf(fminf(r1.x, r1.y), fminf(r1.z, r1.w)));
    }

    float p[2] = { __expf(-2.f * (af[0] - mn[0])), __expf(-2.f * (af[1] - mn[1])) };
    float sm[2] = { p[0], p[1] };
    #pragma unroll
    for (int off = 32; off > 0; off >>= 1) {
        sm[0] += __shfl_xor(sm[0], off, 64);
        sm[1] += __shfl_xor(sm[1], off, 64);
    }
    if ((j & 63) == 0) { s_rB[(ro + 0) * 8 + w8] = sm[0]; s_rB[(ro + 1) * 8 + w8] = sm[1]; }
    __syncthreads();                                         // sync 5
    float n[2];
    #pragma unroll
    for (int ii = 0; ii < 2; ++ii) {
        float4 r0 = *(const float4*)&s_rB[(ro + ii) * 8];
        float4 r1 = *(const float4*)&s_rB[(ro + ii) * 8 + 4];
        float rs = rcp_fast((r0.x + r0.y) + (r0.z + r0.w) + (r1.x + r1.y) + (r1.z + r1.w));
        n[ii] = p[ii] * rs;
        attn[((size_t)b * SL + i0 + ro + ii) * SL + j] = n[ii];   // coalesced
    }
    ((float2*)s_pT)[j * 2 + dh] = make_float2(n[0], n[1]);   // [j][4] row-minor
    __syncthreads();                                         // sync 6

    // ---- Phase 3: out = attn @ inp; wave g covers j = g*32..g*32+31 ----
    const int g  = t >> 6;                  // 16 waves
    const int ln = t & 63;
    const int dq = ln & 31;                 // d-quad (d = dq*4..dq*4+3)
    const int rh = ln >> 5;                 // row pair: rows rh*2, rh*2+1
    const float4* inp4 = (const float4*)(inp + (size_t)b * SL * BD);
    float4 acc0 = make_float4(0.f, 0.f, 0.f, 0.f);
    float4 acc1 = make_float4(0.f, 0.f, 0.f, 0.f);
    #pragma unroll 4
    for (int jjj = 0; jjj < 32; ++jjj) {
        int jr = g * 32 + jjj;
        float4 x  = inp4[jr * 32 + dq];                    // L2-hit b128
        float2 pp = ((const float2*)s_pT)[jr * 2 + rh];    // 2-addr LDS broadcast
        acc0.x = fmaf(pp.x, x.x, acc0.x); acc0.y = fmaf(pp.x, x.y, acc0.y);
        acc0.z = fmaf(pp.x, x.z, acc0.z); acc0.w = fmaf(pp.x, x.w, acc0.w);
        acc1.x = fmaf(pp.y, x.x, acc1.x); acc1.y = fmaf(pp.y, x.y, acc1.y);
        acc1.z = fmaf(pp.y, x.z, acc1.z); acc1.w = fmaf(pp.y, x.w, acc1.w);
    }
    // s_fin overlays s_ap (last read before sync 4); s_pT untouched.
    *(float4*)&s_fin[((g * 4) + rh * 2 + 0) * BD + dq * 4] = acc0;
    *(float4*)&s_fin[((g * 4) + rh * 2 + 1) * BD + dq * 4] = acc1;
    __syncthreads();                                         // sync 7
    if (t < 512) {
        int row = t >> 7, d = t & 127;
        float s = 0.f;
        #pragma unroll
        for (int gg = 0; gg < 16; ++gg)
            s += s_fin[(gg * 4 + row) * BD + d];           // conflict-free
        out[((size_t)b * SL + i0 + row) * BD + d] = s;     // coalesced
    }
}

extern "C" void kernel_launch(void* const* d_in, const int* in_sizes, int n_in,
                              void* d_out, int out_size, void* d_ws, size_t ws_size,
                              hipStream_t stream) {
    const float* inp = (const float*)d_in[0];
    const float* Wu  = (const float*)d_in[1];
    const float* Ww  = (const float*)d_in[2];
    const float* Wv  = (const float*)d_in[3];

    float* out  = (float*)d_out;
    float* attn = out + (size_t)NB * SL * BD;     // out (B,L,D) then attn (B,L,L)

    float* ws   = (float*)d_ws;
    float* Equ2 = ws;                             // (B, D/4, L/2, 8) packed exp(2*qu)
    float* Ekw  = Equ2 + (size_t)NB * BD * SL;    // (B, L, D) exp(2*kw)
    float* WuT  = Ekw + (size_t)NB * SL * BD;
    float* WwT  = WuT + BD * BD;

    k_tr  <<<BD * BD / 256, 256, 0, stream>>>(Wu, Ww, WuT, WwT);
    k_qk  <<<NB * SL / 2, 256, 0, stream>>>(inp, WuT, WwT, Equ2, Ekw);
    k_attn<<<NB * SL / 4, 1024, 0, stream>>>(inp, Wv, Equ2, Ekw, out, attn);
}

// Round 8
// 89.693 us; speedup vs baseline: 1.0684x; 1.0585x over previous
//
#include <hip/hip_runtime.h>

#define BD 128   // D
#define SL 512   // L
#define NB 4     // B

__device__ __forceinline__ float rcp_fast(float x) { return __builtin_amdgcn_rcpf(x); }

// K0: transpose Wu, Ww (row-major (out,in)) -> WT[k][o]. 64 blocks, trivial.
__global__ __launch_bounds__(256) void k_tr(const float* __restrict__ Wu,
                                            const float* __restrict__ Ww,
                                            float* __restrict__ WuT,
                                            float* __restrict__ WwT) {
    int idx = blockIdx.x * 256 + threadIdx.x;   // 0..16383
    int k = idx >> 7, o = idx & 127;
    WuT[idx] = Wu[o * BD + k];
    WwT[idx] = Ww[o * BD + k];
}

// K1: qu = inp@Wu.T, kw = inp@Ww.T. 2 rows/block, 1024 blocks (4/CU).
// Equ2 packed [b][d>>2][j>>1][(j&1)*4 + (d&3)]: k_attn reads a j-pair as 2 b128.
__global__ __launch_bounds__(256) void k_qk(const float* __restrict__ inp,
                                            const float* __restrict__ WuT,
                                            const float* __restrict__ WwT,
                                            float* __restrict__ Equ2,
                                            float* __restrict__ Ekw) {
    __shared__ float sx[2][BD];
    const int t = threadIdx.x, m = t >> 7, o = t & 127;
    const int r0 = blockIdx.x * 2;          // global row = b*SL + l  (l0 even)
    const int b  = r0 >> 9;
    const int l0 = r0 & (SL - 1);
    const int jp = l0 >> 1;

    sx[t >> 7][t & 127] = inp[(size_t)r0 * BD + t];   // coalesced 512 floats
    __syncthreads();

    const float* WT = m ? WwT : WuT;        // WT[k][o], coalesced + L2-hot
    float acc0 = 0.f, acc1 = 0.f;
    #pragma unroll 4
    for (int k = 0; k < BD; k += 4) {       // 16 loads in flight
        float w0 = WT[(k + 0) * BD + o];
        float w1 = WT[(k + 1) * BD + o];
        float w2 = WT[(k + 2) * BD + o];
        float w3 = WT[(k + 3) * BD + o];
        float4 x0 = *(const float4*)&sx[0][k];
        float4 x1 = *(const float4*)&sx[1][k];
        acc0 = fmaf(x0.x, w0, acc0); acc0 = fmaf(x0.y, w1, acc0);
        acc0 = fmaf(x0.z, w2, acc0); acc0 = fmaf(x0.w, w3, acc0);
        acc1 = fmaf(x1.x, w0, acc1); acc1 = fmaf(x1.y, w1, acc1);
        acc1 = fmaf(x1.z, w2, acc1); acc1 = fmaf(x1.w, w3, acc1);
    }

    if (m == 0) {
        size_t base = (((size_t)b * 32 + (o >> 2)) * 256 + jp) * 8 + (o & 3);
        Equ2[base]     = __expf(2.f * acc0);   // jj=0
        Equ2[base + 4] = __expf(2.f * acc1);   // jj=1
    } else {
        Ekw[(size_t)(r0 + 0) * BD + o] = __expf(2.f * acc0);
        Ekw[(size_t)(r0 + 1) * BD + o] = __expf(2.f * acc1);
    }
}

// K2: block = (b, 4 query rows), 1024 threads, 2 blocks/CU.
// P1 paired-rcp: wv/(1+qe) = 1/x, x = fma(q, E, u), E=e/wv... e*u, u=1/wv;
//   1/x0 + 1/x1 = (x0+x1)*rcp(x0*x1)  -> one rcp per two d.
// P2: softmax WITHOUT max-shift (|2a|<=18, exp in range). P3: 16 j-chunk waves.
__global__ __launch_bounds__(1024, 8) void k_attn(const float* __restrict__ inp,
                                                  const float* __restrict__ Wv,
                                                  const float* __restrict__ Equ2,
                                                  const float* __restrict__ Ekw,
                                                  float* __restrict__ out,
                                                  float* __restrict__ attn) {
    __shared__ float  s_pT[SL * 4];        // 8 KB  attn weights [j][4 rows]
    __shared__ float  s_ap[8192];          // 32 KB P1 partials [dg][jj][i][jp]; P3 s_fin
    __shared__ float4 s_E[BD];             // 2 KB  {e_i*u} per d, i=0..3
    __shared__ float  s_u[BD];             // 0.5 KB 1/wv
    __shared__ float  s_rB[4 * 8];         // sum-reduce

    const int t  = threadIdx.x;
    const int b  = blockIdx.x >> 7;
    const int i0 = (blockIdx.x & 127) * 4;

    if (t < BD) {
        const float* ek = Ekw + ((size_t)b * SL + i0) * BD + t;
        float u = rcp_fast(Wv[t]);
        s_E[t] = make_float4(ek[0] * u, ek[BD] * u, ek[2 * BD] * u, ek[3 * BD] * u);
        s_u[t] = u;
    }
    __syncthreads();                                         // B1

    // ---- Phase 1 ----
    const int jp = t & 255, dg = t >> 8;
    const float4* equ4 = (const float4*)(Equ2 + (size_t)b * BD * SL);
    float a0[4] = {0.f, 0.f, 0.f, 0.f};   // j = 2jp
    float a1[4] = {0.f, 0.f, 0.f, 0.f};   // j = 2jp+1
    #pragma unroll 2
    for (int cc = 0; cc < 8; ++cc) {
        int c = dg * 8 + cc;
        float4 qA = equ4[(c * 256 + jp) * 2 + 0];   // j=2jp,   d=4c..4c+3
        float4 qB = equ4[(c * 256 + jp) * 2 + 1];   // j=2jp+1
        float4 E0 = s_E[c * 4 + 0];        // wave-uniform b128 broadcasts
        float4 E1 = s_E[c * 4 + 1];
        float4 E2 = s_E[c * 4 + 2];
        float4 E3 = s_E[c * 4 + 3];
        float4 uu = *(const float4*)&s_u[c * 4];
        float e0[4] = {E0.x, E0.y, E0.z, E0.w};
        float e1[4] = {E1.x, E1.y, E1.z, E1.w};
        float e2[4] = {E2.x, E2.y, E2.z, E2.w};
        float e3[4] = {E3.x, E3.y, E3.z, E3.w};
        #pragma unroll
        for (int i = 0; i < 4; ++i) {
            // j = 2jp : pairs (d0,d1), (d2,d3)
            float xa0 = fmaf(qA.x, e0[i], uu.x);
            float xa1 = fmaf(qA.y, e1[i], uu.y);
            a0[i] = fmaf(xa0 + xa1, rcp_fast(xa0 * xa1), a0[i]);
            float xa2 = fmaf(qA.z, e2[i], uu.z);
            float xa3 = fmaf(qA.w, e3[i], uu.w);
            a0[i] = fmaf(xa2 + xa3, rcp_fast(xa2 * xa3), a0[i]);
            // j = 2jp+1
            float xb0 = fmaf(qB.x, e0[i], uu.x);
            float xb1 = fmaf(qB.y, e1[i], uu.y);
            a1[i] = fmaf(xb0 + xb1, rcp_fast(xb0 * xb1), a1[i]);
            float xb2 = fmaf(qB.z, e2[i], uu.z);
            float xb3 = fmaf(qB.w, e3[i], uu.w);
            a1[i] = fmaf(xb2 + xb3, rcp_fast(xb2 * xb3), a1[i]);
        }
    }
    #pragma unroll
    for (int i = 0; i < 4; ++i) {
        s_ap[((dg * 2 + 0) * 4 + i) * 256 + jp] = a0[i];     // conflict-free
        s_ap[((dg * 2 + 1) * 4 + i) * 256 + jp] = a1[i];
    }
    __syncthreads();                                         // B2

    // ---- Phase 2: softmax over j of score = -2a, no max-shift ----
    const int j = t & 511, dh = t >> 9, ro = dh * 2;
    const int jpp = j >> 1, jj = j & 1, w8 = j >> 6;
    float af[2];
    #pragma unroll
    for (int ii = 0; ii < 2; ++ii) {
        int r = ro + ii;
        af[ii] = s_ap[((0 * 2 + jj) * 4 + r) * 256 + jpp]
               + s_ap[((1 * 2 + jj) * 4 + r) * 256 + jpp]
               + s_ap[((2 * 2 + jj) * 4 + r) * 256 + jpp]
               + s_ap[((3 * 2 + jj) * 4 + r) * 256 + jpp];
    }
    float p0 = __expf(-2.f * af[0]);
    float p1 = __expf(-2.f * af[1]);
    float sm0 = p0, sm1 = p1;
    #pragma unroll
    for (int off = 32; off > 0; off >>= 1) {
        sm0 += __shfl_xor(sm0, off, 64);
        sm1 += __shfl_xor(sm1, off, 64);
    }
    if ((j & 63) == 0) { s_rB[(ro + 0) * 8 + w8] = sm0; s_rB[(ro + 1) * 8 + w8] = sm1; }
    __syncthreads();                                         // B3
    float n0, n1;
    {
        float4 r0 = *(const float4*)&s_rB[(ro + 0) * 8];
        float4 r1 = *(const float4*)&s_rB[(ro + 0) * 8 + 4];
        n0 = p0 * rcp_fast((r0.x + r0.y) + (r0.z + r0.w) + (r1.x + r1.y) + (r1.z + r1.w));
        float4 s0 = *(const float4*)&s_rB[(ro + 1) * 8];
        float4 s1 = *(const float4*)&s_rB[(ro + 1) * 8 + 4];
        n1 = p1 * rcp_fast((s0.x + s0.y) + (s0.z + s0.w) + (s1.x + s1.y) + (s1.z + s1.w));
    }
    attn[((size_t)b * SL + i0 + ro + 0) * SL + j] = n0;      // coalesced
    attn[((size_t)b * SL + i0 + ro + 1) * SL + j] = n1;
    ((float2*)s_pT)[j * 2 + dh] = make_float2(n0, n1);       // [j][4] row-minor
    __syncthreads();                                         // B4

    // ---- Phase 3: out = attn @ inp; wave g covers j = g*32..g*32+31 ----
    const int g  = t >> 6;                  // 16 waves
    const int ln = t & 63;
    const int dq = ln & 31;                 // d-quad
    const int rh = ln >> 5;                 // row pair
    const float4* inp4 = (const float4*)(inp + (size_t)b * SL * BD);
    float4 acc0 = make_float4(0.f, 0.f, 0.f, 0.f);
    float4 acc1 = make_float4(0.f, 0.f, 0.f, 0.f);
    #pragma unroll 4
    for (int jjj = 0; jjj < 32; ++jjj) {
        int jr = g * 32 + jjj;
        float4 x  = inp4[jr * 32 + dq];                    // L2-hit b128
        float2 pp = ((const float2*)s_pT)[jr * 2 + rh];    // 2-addr LDS broadcast
        acc0.x = fmaf(pp.x, x.x, acc0.x); acc0.y = fmaf(pp.x, x.y, acc0.y);
        acc0.z = fmaf(pp.x, x.z, acc0.z); acc0.w = fmaf(pp.x, x.w, acc0.w);
        acc1.x = fmaf(pp.y, x.x, acc1.x); acc1.y = fmaf(pp.y, x.y, acc1.y);
        acc1.z = fmaf(pp.y, x.z, acc1.z); acc1.w = fmaf(pp.y, x.w, acc1.w);
    }
    // s_fin overlays s_ap (last read before B3)
    float* s_fin = s_ap;                    // [16][4][BD]
    *(float4*)&s_fin[((g * 4) + rh * 2 + 0) * BD + dq * 4] = acc0;
    *(float4*)&s_fin[((g * 4) + rh * 2 + 1) * BD + dq * 4] = acc1;
    __syncthreads();                                         // B5
    if (t < 512) {
        int row = t >> 7, d = t & 127;
        float s = 0.f;
        #pragma unroll
        for (int gg = 0; gg < 16; ++gg)
            s += s_fin[(gg * 4 + row) * BD + d];           // conflict-free
        out[((size_t)b * SL + i0 + row) * BD + d] = s;     // coalesced
    }
}

extern "C" void kernel_launch(void* const* d_in, const int* in_sizes, int n_in,
                              void* d_out, int out_size, void* d_ws, size_t ws_size,
                              hipStream_t stream) {
    const float* inp = (const float*)d_in[0];
    const float* Wu  = (const float*)d_in[1];
    const float* Ww  = (const float*)d_in[2];
    const float* Wv  = (const float*)d_in[3];

    float* out  = (float*)d_out;
    float* attn = out + (size_t)NB * SL * BD;     // out (B,L,D) then attn (B,L,L)

    float* ws   = (float*)d_ws;
    float* Equ2 = ws;                             // (B, D/4, L/2, 8) packed exp(2*qu)
    float* Ekw  = Equ2 + (size_t)NB * BD * SL;    // (B, L, D) exp(2*kw)
    float* WuT  = Ekw + (size_t)NB * SL * BD;
    float* WwT  = WuT + BD * BD;

    k_tr  <<<BD * BD / 256, 256, 0, stream>>>(Wu, Ww, WuT, WwT);
    k_qk  <<<NB * SL / 2, 256, 0, stream>>>(inp, WuT, WwT, Equ2, Ekw);
    k_attn<<<NB * SL / 4, 1024, 0, stream>>>(inp, Wv, Equ2, Ekw, out, attn);
}

// Round 9
// 88.555 us; speedup vs baseline: 1.0821x; 1.0128x over previous
//
#include <hip/hip_runtime.h>

#define BD 128   // D
#define SL 512   // L
#define NB 4     // B

__device__ __forceinline__ float rcp_fast(float x) { return __builtin_amdgcn_rcpf(x); }

// K0: transpose Wu, Ww (row-major (out,in)) -> WT[k][o]. 64 blocks, trivial.
__global__ __launch_bounds__(256) void k_tr(const float* __restrict__ Wu,
                                            const float* __restrict__ Ww,
                                            float* __restrict__ WuT,
                                            float* __restrict__ WwT) {
    int idx = blockIdx.x * 256 + threadIdx.x;   // 0..16383
    int k = idx >> 7, o = idx & 127;
    WuT[idx] = Wu[o * BD + k];
    WwT[idx] = Ww[o * BD + k];
}

// K1: qu = inp@Wu.T, kw = inp@Ww.T. 2 rows/block, 1024 blocks (4/CU).
// XCD-aware swizzle: batch b pinned to XCD pair {2b, 2b+1} (blk%8 = XCD heuristic)
// so Equ2/Ekw writes land in the L2 that k_attn will read them from.
// Equ2 packed [b][d>>2][j>>1][(j&1)*4 + (d&3)]: k_attn reads a j-pair as 2 b128.
__global__ __launch_bounds__(256) void k_qk(const float* __restrict__ inp,
                                            const float* __restrict__ WuT,
                                            const float* __restrict__ WwT,
                                            float* __restrict__ Equ2,
                                            float* __restrict__ Ekw) {
    __shared__ float sx[2][BD];
    const int t = threadIdx.x, m = t >> 7, o = t & 127;
    const int blk = blockIdx.x;
    const int x   = blk & 7;                // XCD (round-robin heuristic)
    const int b   = x >> 1;                 // batch pinned to XCD pair
    const int rp  = (blk >> 3) * 2 + (x & 1);   // row-pair 0..255
    const int r0  = b * SL + rp * 2;        // global row (even)
    const int l0  = rp * 2;
    const int jp  = l0 >> 1;

    sx[t >> 7][t & 127] = inp[(size_t)r0 * BD + t];   // coalesced 512 floats
    __syncthreads();

    const float* WT = m ? WwT : WuT;        // WT[k][o], coalesced + L2-hot
    float acc0 = 0.f, acc1 = 0.f;
    #pragma unroll 4
    for (int k = 0; k < BD; k += 4) {       // 16 loads in flight
        float w0 = WT[(k + 0) * BD + o];
        float w1 = WT[(k + 1) * BD + o];
        float w2 = WT[(k + 2) * BD + o];
        float w3 = WT[(k + 3) * BD + o];
        float4 x0 = *(const float4*)&sx[0][k];
        float4 x1 = *(const float4*)&sx[1][k];
        acc0 = fmaf(x0.x, w0, acc0); acc0 = fmaf(x0.y, w1, acc0);
        acc0 = fmaf(x0.z, w2, acc0); acc0 = fmaf(x0.w, w3, acc0);
        acc1 = fmaf(x1.x, w0, acc1); acc1 = fmaf(x1.y, w1, acc1);
        acc1 = fmaf(x1.z, w2, acc1); acc1 = fmaf(x1.w, w3, acc1);
    }

    if (m == 0) {
        size_t base = (((size_t)b * 32 + (o >> 2)) * 256 + jp) * 8 + (o & 3);
        Equ2[base]     = __expf(2.f * acc0);   // jj=0
        Equ2[base + 4] = __expf(2.f * acc1);   // jj=1
    } else {
        Ekw[(size_t)(r0 + 0) * BD + o] = __expf(2.f * acc0);
        Ekw[(size_t)(r0 + 1) * BD + o] = __expf(2.f * acc1);
    }
}

// K2: block = (b, 4 query rows), 1024 threads, 2 blocks/CU.
// XCD-aware swizzle: batch b pinned to XCD pair {2b,2b+1} -> per-XCD L2 working set
// = Equ2(b) 1MB + inp(b) 1MB + Ekw(b) 1MB = 3MB <= 4MB -> phase-1/3 reads L2-local.
// P1 paired-rcp: one rcp per two d. P2: softmax w/o max-shift. P3: 16 j-chunk waves.
__global__ __launch_bounds__(1024, 8) void k_attn(const float* __restrict__ inp,
                                                  const float* __restrict__ Wv,
                                                  const float* __restrict__ Equ2,
                                                  const float* __restrict__ Ekw,
                                                  float* __restrict__ out,
                                                  float* __restrict__ attn) {
    __shared__ float  s_pT[SL * 4];        // 8 KB  attn weights [j][4 rows]
    __shared__ float  s_ap[8192];          // 32 KB P1 partials; P3 s_fin
    __shared__ float4 s_E[BD];             // 2 KB  {e_i*u} per d, i=0..3
    __shared__ float  s_u[BD];             // 0.5 KB 1/wv
    __shared__ float  s_rB[4 * 8];         // sum-reduce

    const int t   = threadIdx.x;
    const int blk = blockIdx.x;
    const int x   = blk & 7;                // XCD
    const int b   = x >> 1;                 // batch pinned to XCD pair
    const int it  = (blk >> 3) * 2 + (x & 1);   // i-tile 0..127
    const int i0  = it * 4;

    if (t < BD) {
        const float* ek = Ekw + ((size_t)b * SL + i0) * BD + t;
        float u = rcp_fast(Wv[t]);
        s_E[t] = make_float4(ek[0] * u, ek[BD] * u, ek[2 * BD] * u, ek[3 * BD] * u);
        s_u[t] = u;
    }
    __syncthreads();                                         // B1

    // ---- Phase 1 ----
    const int jp = t & 255, dg = t >> 8;
    const float4* equ4 = (const float4*)(Equ2 + (size_t)b * BD * SL);
    float a0[4] = {0.f, 0.f, 0.f, 0.f};   // j = 2jp
    float a1[4] = {0.f, 0.f, 0.f, 0.f};   // j = 2jp+1
    #pragma unroll 2
    for (int cc = 0; cc < 8; ++cc) {
        int c = dg * 8 + cc;
        float4 qA = equ4[(c * 256 + jp) * 2 + 0];   // j=2jp,   d=4c..4c+3
        float4 qB = equ4[(c * 256 + jp) * 2 + 1];   // j=2jp+1
        float4 E0 = s_E[c * 4 + 0];        // wave-uniform b128 broadcasts
        float4 E1 = s_E[c * 4 + 1];
        float4 E2 = s_E[c * 4 + 2];
        float4 E3 = s_E[c * 4 + 3];
        float4 uu = *(const float4*)&s_u[c * 4];
        float e0[4] = {E0.x, E0.y, E0.z, E0.w};
        float e1[4] = {E1.x, E1.y, E1.z, E1.w};
        float e2[4] = {E2.x, E2.y, E2.z, E2.w};
        float e3[4] = {E3.x, E3.y, E3.z, E3.w};
        #pragma unroll
        for (int i = 0; i < 4; ++i) {
            float xa0 = fmaf(qA.x, e0[i], uu.x);
            float xa1 = fmaf(qA.y, e1[i], uu.y);
            a0[i] = fmaf(xa0 + xa1, rcp_fast(xa0 * xa1), a0[i]);
            float xa2 = fmaf(qA.z, e2[i], uu.z);
            float xa3 = fmaf(qA.w, e3[i], uu.w);
            a0[i] = fmaf(xa2 + xa3, rcp_fast(xa2 * xa3), a0[i]);
            float xb0 = fmaf(qB.x, e0[i], uu.x);
            float xb1 = fmaf(qB.y, e1[i], uu.y);
            a1[i] = fmaf(xb0 + xb1, rcp_fast(xb0 * xb1), a1[i]);
            float xb2 = fmaf(qB.z, e2[i], uu.z);
            float xb3 = fmaf(qB.w, e3[i], uu.w);
            a1[i] = fmaf(xb2 + xb3, rcp_fast(xb2 * xb3), a1[i]);
        }
    }
    #pragma unroll
    for (int i = 0; i < 4; ++i) {
        s_ap[((dg * 2 + 0) * 4 + i) * 256 + jp] = a0[i];     // conflict-free
        s_ap[((dg * 2 + 1) * 4 + i) * 256 + jp] = a1[i];
    }
    __syncthreads();                                         // B2

    // ---- Phase 2: softmax over j of score = -2a, no max-shift ----
    const int j = t & 511, dh = t >> 9, ro = dh * 2;
    const int jpp = j >> 1, jj = j & 1, w8 = j >> 6;
    float af[2];
    #pragma unroll
    for (int ii = 0; ii < 2; ++ii) {
        int r = ro + ii;
        af[ii] = s_ap[((0 * 2 + jj) * 4 + r) * 256 + jpp]
               + s_ap[((1 * 2 + jj) * 4 + r) * 256 + jpp]
               + s_ap[((2 * 2 + jj) * 4 + r) * 256 + jpp]
               + s_ap[((3 * 2 + jj) * 4 + r) * 256 + jpp];
    }
    float p0 = __expf(-2.f * af[0]);
    float p1 = __expf(-2.f * af[1]);
    float sm0 = p0, sm1 = p1;
    #pragma unroll
    for (int off = 32; off > 0; off >>= 1) {
        sm0 += __shfl_xor(sm0, off, 64);
        sm1 += __shfl_xor(sm1, off, 64);
    }
    if ((j & 63) == 0) { s_rB[(ro + 0) * 8 + w8] = sm0; s_rB[(ro + 1) * 8 + w8] = sm1; }
    __syncthreads();                                         // B3
    float n0, n1;
    {
        float4 r0 = *(const float4*)&s_rB[(ro + 0) * 8];
        float4 r1 = *(const float4*)&s_rB[(ro + 0) * 8 + 4];
        n0 = p0 * rcp_fast((r0.x + r0.y) + (r0.z + r0.w) + (r1.x + r1.y) + (r1.z + r1.w));
        float4 s0 = *(const float4*)&s_rB[(ro + 1) * 8];
        float4 s1 = *(const float4*)&s_rB[(ro + 1) * 8 + 4];
        n1 = p1 * rcp_fast((s0.x + s0.y) + (s0.z + s0.w) + (s1.x + s1.y) + (s1.z + s1.w));
    }
    attn[((size_t)b * SL + i0 + ro + 0) * SL + j] = n0;      // coalesced
    attn[((size_t)b * SL + i0 + ro + 1) * SL + j] = n1;
    ((float2*)s_pT)[j * 2 + dh] = make_float2(n0, n1);       // [j][4] row-minor
    __syncthreads();                                         // B4

    // ---- Phase 3: out = attn @ inp; wave g covers j = g*32..g*32+31 ----
    const int g  = t >> 6;                  // 16 waves
    const int ln = t & 63;
    const int dq = ln & 31;                 // d-quad
    const int rh = ln >> 5;                 // row pair
    const float4* inp4 = (const float4*)(inp + (size_t)b * SL * BD);
    float4 acc0 = make_float4(0.f, 0.f, 0.f, 0.f);
    float4 acc1 = make_float4(0.f, 0.f, 0.f, 0.f);
    #pragma unroll 4
    for (int jjj = 0; jjj < 32; ++jjj) {
        int jr = g * 32 + jjj;
        float4 xv = inp4[jr * 32 + dq];                    // L2-local b128
        float2 pp = ((const float2*)s_pT)[jr * 2 + rh];    // 2-addr LDS broadcast
        acc0.x = fmaf(pp.x, xv.x, acc0.x); acc0.y = fmaf(pp.x, xv.y, acc0.y);
        acc0.z = fmaf(pp.x, xv.z, acc0.z); acc0.w = fmaf(pp.x, xv.w, acc0.w);
        acc1.x = fmaf(pp.y, xv.x, acc1.x); acc1.y = fmaf(pp.y, xv.y, acc1.y);
        acc1.z = fmaf(pp.y, xv.z, acc1.z); acc1.w = fmaf(pp.y, xv.w, acc1.w);
    }
    float* s_fin = s_ap;                    // [16][4][BD] overlays s_ap
    *(float4*)&s_fin[((g * 4) + rh * 2 + 0) * BD + dq * 4] = acc0;
    *(float4*)&s_fin[((g * 4) + rh * 2 + 1) * BD + dq * 4] = acc1;
    __syncthreads();                                         // B5
    if (t < 512) {
        int row = t >> 7, d = t & 127;
        float s = 0.f;
        #pragma unroll
        for (int gg = 0; gg < 16; ++gg)
            s += s_fin[(gg * 4 + row) * BD + d];           // conflict-free
        out[((size_t)b * SL + i0 + row) * BD + d] = s;     // coalesced
    }
}

extern "C" void kernel_launch(void* const* d_in, const int* in_sizes, int n_in,
                              void* d_out, int out_size, void* d_ws, size_t ws_size,
                              hipStream_t stream) {
    const float* inp = (const float*)d_in[0];
    const float* Wu  = (const float*)d_in[1];
    const float* Ww  = (const float*)d_in[2];
    const float* Wv  = (const float*)d_in[3];

    float* out  = (float*)d_out;
    float* attn = out + (size_t)NB * SL * BD;     // out (B,L,D) then attn (B,L,L)

    float* ws   = (float*)d_ws;
    float* Equ2 = ws;                             // (B, D/4, L/2, 8) packed exp(2*qu)
    float* Ekw  = Equ2 + (size_t)NB * BD * SL;    // (B, L, D) exp(2*kw)
    float* WuT  = Ekw + (size_t)NB * SL * BD;
    float* WwT  = WuT + BD * BD;

    k_tr  <<<BD * BD / 256, 256, 0, stream>>>(Wu, Ww, WuT, WwT);
    k_qk  <<<NB * SL / 2, 256, 0, stream>>>(inp, WuT, WwT, Equ2, Ekw);
    k_attn<<<NB * SL / 4, 1024, 0, stream>>>(inp, Wv, Equ2, Ekw, out, attn);
}